// Round 5
// baseline (241.898 us; speedup 1.0000x reference)
//
#include <hip/hip_runtime.h>
#include <hip/hip_bf16.h>

#define NB 8192     // batch
#define IC 32       // input capsules
#define ID 288      // input dims (K)
#define OD16 160    // OUT_CAPS*OUT_DIMS (N)

typedef __attribute__((ext_vector_type(8))) short bf16x8;
typedef __attribute__((ext_vector_type(4))) float f32x4;

__device__ __forceinline__ unsigned short f2bf(float f) {
    unsigned int u = __builtin_bit_cast(unsigned int, f);
    u = u + 0x7fffu + ((u >> 16) & 1u);   // round-to-nearest-even
    return (unsigned short)(u >> 16);
}
__device__ __forceinline__ float bf2f(unsigned short h) {
    return __builtin_bit_cast(float, ((unsigned int)h) << 16);
}
// 8 floats -> 8 bf16 via v_cvt_pk_bf16_f32 (compiler-generated)
__device__ __forceinline__ bf16x8 cvt_bf8(const float4& a, const float4& b) {
    union { __hip_bfloat162 h[4]; bf16x8 v; } u;
    u.h[0] = __float22bfloat162_rn(make_float2(a.x, a.y));
    u.h[1] = __float22bfloat162_rn(make_float2(a.z, a.w));
    u.h[2] = __float22bfloat162_rn(make_float2(b.x, b.y));
    u.h[3] = __float22bfloat162_rn(make_float2(b.z, b.w));
    return u.v;
}

// ---------------------------------------------------------------------------
// prep: one block per (c, s). LDS-transpose W's [kw x 160] f32 tile to bf16,
// write Wt2[c][n=160][k=288] (transposed, k-contiguous, no padding needed:
// 288 = 9*32). Block 0 additionally zeros a_part[3][8][320].
// ---------------------------------------------------------------------------
__global__ __launch_bounds__(256) void prep_kernel(const float* __restrict__ W,
                                                   unsigned short* __restrict__ Wt2,
                                                   float* __restrict__ a_arr) {
    __shared__ short tile[160 * 72];   // row n: 64 k-shorts (+pad), 144B stride
    const int bx = blockIdx.x;
    const int c = bx / 5;
    const int s = bx - c * 5;
    const int t = threadIdx.x;
    if (bx == 0) {
        for (int i = t; i < 3 * 8 * 320; i += 256) a_arr[i] = 0.f;
    }
    const int kw = (s == 4) ? 32 : 64;
    const int nel = kw * 160;
    for (int idx = t; idx < nel; idx += 256) {
        int k = idx / 160;
        int n = idx - k * 160;
        tile[n * 72 + k] = (short)f2bf(W[((long)c * ID + s * 64 + k) * OD16 + n]);
    }
    __syncthreads();
    const int ng = (kw / 8) * 160;          // 16B granules to emit
    const int gpr = kw / 8;                 // granules per n-row
    for (int p = t; p < ng; p += 256) {
        int n = p / gpr;
        int g = p - n * gpr;
        *(uint4*)(Wt2 + ((long)c * 160 + n) * ID + s * 64 + g * 8) =
            *(const uint4*)&tile[n * 72 + g * 8];
    }
}

// ---------------------------------------------------------------------------
// gemm: u_hat[c][b][od] = data[b][c][:] @ W[c][:][od], bf16 MFMA 16x16x32.
// Barrier-free main loop: A and B both global->reg with 1-kc-ahead register
// double-buffers; B reads are 16-full-line instructions from Wt2 (L1/L2-
// resident, 92 KB/capsule). LDS (20 KB) used only for the two-round
// epilogue staging -> 8 blocks/CU, waves fully independent.
// ---------------------------------------------------------------------------
__global__ __launch_bounds__(256) void gemm_kernel(const float* __restrict__ data,
                                                   const unsigned short* __restrict__ Wt2,
                                                   unsigned short* __restrict__ uhat) {
    __shared__ alignas(16) short eb[64 * 160];   // 20480 B
    const int tid = threadIdx.x;
    const int lane = tid & 63;
    const int w = tid >> 6;
    const int q = lane >> 4;     // 0..3
    const int r = lane & 15;
    const int b0 = blockIdx.x * 128;
    const int cc = blockIdx.y;

    const float* A0 = data + (long)(b0 + w * 32 + r) * (IC * ID) + cc * ID + q * 8;  // mf=0 row
    const float* A1 = A0 + 16 * (IC * ID);                                           // mf=1 row
    const unsigned short* B0 = Wt2 + ((long)cc * 160 + r) * ID + q * 8;

    f32x4 acc[2][10];
    #pragma unroll
    for (int i = 0; i < 2; ++i)
        #pragma unroll
        for (int j = 0; j < 10; ++j)
            acc[i][j] = (f32x4){0.f, 0.f, 0.f, 0.f};

    float4 av[2][2][2];   // [bank][mf][half]
    bf16x8 bv[2][10];     // [bank][nf]

    #define LOADA(BANK, KC)                                                    \
        {                                                                      \
            av[BANK][0][0] = *(const float4*)(A0 + (KC) * 32);                 \
            av[BANK][0][1] = *(const float4*)(A0 + (KC) * 32 + 4);             \
            av[BANK][1][0] = *(const float4*)(A1 + (KC) * 32);                 \
            av[BANK][1][1] = *(const float4*)(A1 + (KC) * 32 + 4);             \
        }
    #define LOADB(BANK, KC)                                                    \
        {                                                                      \
            _Pragma("unroll")                                                  \
            for (int nf = 0; nf < 10; ++nf)                                    \
                bv[BANK][nf] = *(const bf16x8*)(B0 + (long)nf * (16 * ID) + (KC) * 32); \
        }

    LOADA(0, 0)
    LOADB(0, 0)
    #pragma unroll
    for (int kc = 0; kc < 9; ++kc) {
        const int bank = kc & 1;
        if (kc < 8) {
            LOADA(bank ^ 1, kc + 1)
            LOADB(bank ^ 1, kc + 1)
        }
        bf16x8 af0 = cvt_bf8(av[bank][0][0], av[bank][0][1]);
        bf16x8 af1 = cvt_bf8(av[bank][1][0], av[bank][1][1]);
        #pragma unroll
        for (int nf = 0; nf < 10; ++nf) {
            acc[0][nf] = __builtin_amdgcn_mfma_f32_16x16x32_bf16(af0, bv[bank][nf], acc[0][nf], 0, 0, 0);
            acc[1][nf] = __builtin_amdgcn_mfma_f32_16x16x32_bf16(af1, bv[bank][nf], acc[1][nf], 0, 0, 0);
        }
    }
    #undef LOADA
    #undef LOADB

    // epilogue: C/D layout col=lane&15 (N), row=q*4+reg (M). Two rounds
    // (one per mf) through 20KB LDS, contiguous 16B stores to uhat[c][b][od].
    unsigned short* dstc = uhat + ((long)cc * NB + b0) * 160;
    #pragma unroll
    for (int mf = 0; mf < 2; ++mf) {
        __syncthreads();
        #pragma unroll
        for (int rr = 0; rr < 4; ++rr) {
            const int lr = w * 16 + (q << 2) + rr;   // local row 0..63
            #pragma unroll
            for (int nf = 0; nf < 10; ++nf)
                eb[lr * 160 + nf * 16 + r] = (short)f2bf(acc[mf][nf][rr]);
        }
        __syncthreads();
        #pragma unroll
        for (int j = 0; j < 5; ++j) {
            const int chunk = j * 256 + tid;         // 1280 uint4
            const int lr = chunk / 20;
            const int p = chunk - lr * 20;
            const int g = ((lr >> 4) << 5) + mf * 16 + (lr & 15);  // global row in tile
            *(uint4*)(dstc + (long)g * 160 + p * 8) = *(const uint4*)(eb + lr * 160 + p * 8);
        }
    }
}

// ---------------------------------------------------------------------------
// route: one wave per batch row, grid 2048x256. uhat layout [i][b][od]
// (plane stride PL). Softmax from 8-way-spread a partials; agreement u
// fragments preloaded to regs (overlap v-phase); v via tiny LDS; block-
// reduced a partials -> 320 atomics/block onto a_out[blockIdx&7].
// ---------------------------------------------------------------------------
template <int COMPUTE_A, int WRITE_V>
__global__ __launch_bounds__(256) void route_kernel(const unsigned short* __restrict__ uhat,
                                                    const float* __restrict__ a_all,  // [n_prev][8][320]
                                                    int n_prev,
                                                    float* __restrict__ a_out,        // [8][320]
                                                    float* __restrict__ v_out) {
    constexpr long PL = (long)NB * 160;   // i-plane stride (shorts)
    __shared__ float c_sh[320];
    __shared__ float v_lds[4][160];
    __shared__ float a_sh[4][320];
    const int tid = threadIdx.x;
    // --- softmax over input capsules (groups of 32, lane-aligned) ---
    for (int base = 0; base < 320; base += 256) {
        int t = base + tid;
        if (t < 320) {
            float bv = 0.f;
            for (int j = 0; j < n_prev * 8; ++j) bv += a_all[j * 320 + t];
            bv *= (1.0f / 8192.0f);
            float m = bv;
            #pragma unroll
            for (int off = 1; off < 32; off <<= 1) m = fmaxf(m, __shfl_xor(m, off));
            float e = __expf(bv - m);
            float ssum = e;
            #pragma unroll
            for (int off = 1; off < 32; off <<= 1) ssum += __shfl_xor(ssum, off);
            c_sh[t] = e / ssum;
        }
    }
    __syncthreads();

    const int w = tid >> 6;
    const int lane = tid & 63;
    const long row = (long)blockIdx.x * 4 + w;
    const unsigned short* __restrict__ u = uhat + row * 160;

    // preload agreement fragments: lane -> (i = lane&31, oo = (lane>>5)+2*s5)
    ushort4 ua[5][4];
    if (COMPUTE_A) {
        #pragma unroll
        for (int s5 = 0; s5 < 5; ++s5) {
            const int i = lane & 31;
            const int oo = (lane >> 5) + 2 * s5;
            #pragma unroll
            for (int d4 = 0; d4 < 4; ++d4)
                ua[s5][d4] = *(const ushort4*)(u + (long)i * PL + oo * 16 + d4 * 4);
        }
    }

    // v-phase: lanes 0..39, lane q owns od-quad q
    if (lane < 40) {
        const int q = lane;
        const int o = q >> 2;
        float4 sv = {0.f, 0.f, 0.f, 0.f};
        #pragma unroll 8
        for (int i = 0; i < 32; ++i) {
            ushort4 uu = *(const ushort4*)(u + (long)i * PL + q * 4);
            float ci = c_sh[o * 32 + i];
            sv.x += ci * bf2f(uu.x);
            sv.y += ci * bf2f(uu.y);
            sv.z += ci * bf2f(uu.z);
            sv.w += ci * bf2f(uu.w);
        }
        if (WRITE_V) *(float4*)(v_out + row * 160 + q * 4) = sv;
        if (COMPUTE_A) *(float4*)(&v_lds[w][q * 4]) = sv;
    }

    if (COMPUTE_A) {
        asm volatile("s_waitcnt lgkmcnt(0)" ::: "memory");  // v_lds visible wave-locally
        #pragma unroll
        for (int s5 = 0; s5 < 5; ++s5) {
            const int i = lane & 31;
            const int oo = (lane >> 5) + 2 * s5;
            const float* vp = &v_lds[w][oo * 16];
            float accv = 0.f;
            #pragma unroll
            for (int d4 = 0; d4 < 4; ++d4) {
                ushort4 uu = ua[s5][d4];
                float4 vv = *(const float4*)(vp + d4 * 4);
                float p0 = bf2f(uu.x) * vv.x;
                float p1 = bf2f(uu.y) * vv.y;
                float p2 = bf2f(uu.z) * vv.z;
                float p3 = bf2f(uu.w) * vv.w;
                accv += p0 * p0 + p1 * p1 + p2 * p2 + p3 * p3;
            }
            a_sh[w][oo * 32 + i] = sqrtf(accv);
        }
        __syncthreads();
        for (int t = tid; t < 320; t += 256) {
            float s4 = a_sh[0][t] + a_sh[1][t] + a_sh[2][t] + a_sh[3][t];
            atomicAdd(a_out + (blockIdx.x & 7) * 320 + t, s4);
        }
    }
}

// ---------------------------------------------------------------------------
extern "C" void kernel_launch(void* const* d_in, const int* in_sizes, int n_in,
                              void* d_out, int out_size, void* d_ws, size_t ws_size,
                              hipStream_t stream) {
    const float* data = (const float*)d_in[0];
    const float* W = (const float*)d_in[1];
    float* out = (float*)d_out;
    char* ws = (char*)d_ws;

    unsigned short* uhat = (unsigned short*)ws;           // [32][8192][160] bf16, 83,886,080 B
    size_t off = (size_t)NB * IC * OD16 * 2;
    unsigned short* Wt2 = (unsigned short*)(ws + off);    // [32][160][288] bf16, 2,949,120 B
    off += (size_t)IC * 160 * ID * 2;
    float* a_arr = (float*)(ws + off); off += 3 * 8 * 320 * 4;  // [it][8][320]

    hipLaunchKernelGGL(prep_kernel, dim3(160), dim3(256), 0, stream, W, Wt2, a_arr);
    hipLaunchKernelGGL(gemm_kernel, dim3(64, 32), dim3(256), 0, stream, data, Wt2, uhat);
    hipLaunchKernelGGL((route_kernel<1, 0>), dim3(2048), dim3(256), 0, stream,
                       uhat, a_arr, 0, a_arr + 0 * 2560, out);
    hipLaunchKernelGGL((route_kernel<1, 0>), dim3(2048), dim3(256), 0, stream,
                       uhat, a_arr, 1, a_arr + 1 * 2560, out);
    hipLaunchKernelGGL((route_kernel<0, 1>), dim3(2048), dim3(256), 0, stream,
                       uhat, a_arr, 2, a_arr + 2 * 2560, out);
}

// Round 6
// 165.508 us; speedup vs baseline: 1.4615x; 1.4615x over previous
//
#include <hip/hip_runtime.h>
#include <hip/hip_bf16.h>

#define NB 8192     // batch
#define IC 32       // input capsules
#define ID 288      // input dims (K)
#define OD16 160    // OUT_CAPS*OUT_DIMS (N)

typedef __attribute__((ext_vector_type(8))) short bf16x8;
typedef __attribute__((ext_vector_type(4))) float f32x4;

__device__ __forceinline__ unsigned short f2bf(float f) {
    unsigned int u = __builtin_bit_cast(unsigned int, f);
    u = u + 0x7fffu + ((u >> 16) & 1u);   // round-to-nearest-even
    return (unsigned short)(u >> 16);
}
__device__ __forceinline__ float bf2f(unsigned short h) {
    return __builtin_bit_cast(float, ((unsigned int)h) << 16);
}
// 8 floats -> 8 bf16 via v_cvt_pk_bf16_f32 (compiler-generated)
__device__ __forceinline__ bf16x8 cvt_bf8(const f32x4& a, const f32x4& b) {
    union { __hip_bfloat162 h[4]; bf16x8 v; } u;
    u.h[0] = __float22bfloat162_rn(make_float2(a[0], a[1]));
    u.h[1] = __float22bfloat162_rn(make_float2(a[2], a[3]));
    u.h[2] = __float22bfloat162_rn(make_float2(b[0], b[1]));
    u.h[3] = __float22bfloat162_rn(make_float2(b[2], b[3]));
    return u.v;
}

__device__ __forceinline__ void gld_lds16(const void* g, void* l) {
    __builtin_amdgcn_global_load_lds((const __attribute__((address_space(1))) unsigned int*)g,
                                     (__attribute__((address_space(3))) unsigned int*)l, 16, 0, 0);
}

// ---------------------------------------------------------------------------
// prep: one block per (c, s). LDS-transpose W's [kw x 160] f32 tile into
// bf16, emit the "LDS image" WtImg[c][s][10240 shorts]: linear byte b holds
// granule (n = b>>7, g = ((b>>4)&7) ^ (n&7)) so a linear global_load_lds
// dest + XOR-swizzled ds_read reconstructs B. K padded 288->320 with zeros.
// Block 0 additionally zeros a_part[3][8][320].
// ---------------------------------------------------------------------------
__global__ __launch_bounds__(256) void prep_kernel(const float* __restrict__ W,
                                                   unsigned short* __restrict__ WtImg,
                                                   float* __restrict__ a_arr) {
    __shared__ short tile[160 * 72];   // row n: 64 k-shorts (+pad), 144B stride
    const int bx = blockIdx.x;
    const int c = bx / 5;
    const int s = bx - c * 5;
    const int t = threadIdx.x;
    if (bx == 0) {
        for (int i = t; i < 3 * 8 * 320; i += 256) a_arr[i] = 0.f;
    }
    const int kw = (s == 4) ? 32 : 64;
    const int nel = kw * 160;
    for (int idx = t; idx < nel; idx += 256) {
        int k = idx / 160;
        int n = idx - k * 160;
        tile[n * 72 + k] = (short)f2bf(W[((long)c * ID + s * 64 + k) * OD16 + n]);
    }
    __syncthreads();
    unsigned short* dst = WtImg + ((long)c * 5 + s) * 10240;
    for (int p = t; p < 1280; p += 256) {
        int n = p >> 3;
        int g = (p & 7) ^ (n & 7);
        uint4 val = make_uint4(0u, 0u, 0u, 0u);
        if (g * 8 < kw) val = *(const uint4*)&tile[n * 72 + g * 8];
        *(uint4*)(dst + p * 8) = val;
    }
}

// ---------------------------------------------------------------------------
// gemm: u_hat[c][b][od] = data[b][c][:] @ W[c][:][od], bf16 MFMA 16x16x32.
// A: f32 staged to WAVE-PRIVATE LDS slices via global_load_lds (full-line
//    coalesced: 8 rows x 128B per DMA instr), double-buffered per kc (K=32),
//    pre-swizzled global source + XOR-swizzled ds_read_b128, cvt on read.
// B: bf16 image staged to shared LDS (K=64 stages), double-buffered.
// Counted vmcnt(9) per kc, 2 raw barriers per K=64 stage; DMA never drains.
// LDS: A 4w*2*4KB=32KB + B 2*20KB=40KB = 72KB -> 2 blocks/CU.
// ---------------------------------------------------------------------------
__global__ __launch_bounds__(256) void gemm_kernel(const float* __restrict__ data,
                                                   const unsigned short* __restrict__ WtImg,
                                                   unsigned short* __restrict__ uhat) {
    __shared__ alignas(16) char lds[73728];   // [0,32768): A, [32768,73728): B
    char* const Alds = lds;
    char* const Blds = lds + 32768;
    const int tid = threadIdx.x;
    const int lane = tid & 63;
    const int w = tid >> 6;
    const int q = lane >> 4;     // 0..3
    const int r = lane & 15;
    const int b0 = blockIdx.x * 128;
    const int cc = blockIdx.y;

    // A DMA source: lane ℓ covers (row = w*32 + j*8 + (ℓ>>3), chunk (ℓ&7)^((ℓ>>3)&7))
    const float* Ag = data + (long)(b0 + w * 32 + (lane >> 3)) * (IC * ID) + cc * ID
                      + ((lane & 7) ^ ((lane >> 3) & 7)) * 4;
    const unsigned short* Wc = WtImg + (long)cc * 51200;

    f32x4 acc[2][10];
    #pragma unroll
    for (int i = 0; i < 2; ++i)
        #pragma unroll
        for (int j = 0; j < 10; ++j)
            acc[i][j] = (f32x4){0.f, 0.f, 0.f, 0.f};

    auto issueA = [&](int buf, int kc) {   // 4 DMA ops, wave-private slice
        char* dst = Alds + w * 8192 + buf * 4096;
        const float* src = Ag + kc * 32;
        #pragma unroll
        for (int j = 0; j < 4; ++j)
            gld_lds16(src + (long)j * 8 * (IC * ID), dst + j * 1024);
    };
    auto issueB = [&](int buf, int s) {    // 5 DMA ops, cooperative
        const unsigned short* src = Wc + s * 10240 + (w * 5) * 512 + lane * 8;
        char* dst = Blds + buf * 20480 + (w * 5) * 1024;
        #pragma unroll
        for (int j = 0; j < 5; ++j)
            gld_lds16(src + j * 512, dst + j * 1024);
    };

#define COMPUTE(KC)                                                            \
    {                                                                          \
        const char* Ab = Alds + w * 8192 + ((KC) & 1) * 4096;                  \
        const char* Bb = Blds + (((KC) >> 1) & 1) * 20480;                     \
        const int kb = ((KC) & 1) * 64 + q * 16;                               \
        bf16x8 bfr[10];                                                        \
        _Pragma("unroll")                                                      \
        for (int nf = 0; nf < 10; ++nf) {                                      \
            const int n = nf * 16 + r;                                         \
            bfr[nf] = *(const bf16x8*)(Bb + ((n * 128 + kb) ^ ((n & 7) << 4)));\
        }                                                                      \
        bf16x8 af[2];                                                          \
        _Pragma("unroll")                                                      \
        for (int mf = 0; mf < 2; ++mf) {                                       \
            const int row = mf * 16 + r;                                       \
            const int c0 = (q * 2) ^ (r & 7);                                  \
            const int c1 = (q * 2 + 1) ^ (r & 7);                              \
            f32x4 alo = *(const f32x4*)(Ab + row * 128 + c0 * 16);             \
            f32x4 ahi = *(const f32x4*)(Ab + row * 128 + c1 * 16);             \
            af[mf] = cvt_bf8(alo, ahi);                                        \
        }                                                                      \
        _Pragma("unroll")                                                      \
        for (int nf = 0; nf < 10; ++nf) {                                      \
            acc[0][nf] = __builtin_amdgcn_mfma_f32_16x16x32_bf16(af[0], bfr[nf], acc[0][nf], 0, 0, 0); \
            acc[1][nf] = __builtin_amdgcn_mfma_f32_16x16x32_bf16(af[1], bfr[nf], acc[1][nf], 0, 0, 0); \
        }                                                                      \
    }

#define WAITV(N)  { asm volatile("s_waitcnt vmcnt(" N ")" ::: "memory");       \
                    __builtin_amdgcn_sched_barrier(0); }
#define BAR()     { __builtin_amdgcn_s_barrier(); }

    // prologue: FIFO order A0,B0,A1,B1  (outstanding 18)
    issueA(0, 0); issueB(0, 0); issueA(1, 1); issueB(1, 1);
    // kc0 (even, s=0): A0+B0 landed, A1+B1 stay in flight
    WAITV("9") BAR() COMPUTE(0)
    // kc1 (odd): issue A2 -> [A1,B1,A2]; wait A1
    issueA(0, 2); WAITV("9") COMPUTE(1) BAR()
    // kc2 (even, s=1): issue A3,B2 -> [B1,A2,A3,B2]; wait B1,A2
    issueA(1, 3); issueB(0, 2); WAITV("9") BAR() COMPUTE(2)
    // kc3: A4 -> [A3,B2,A4]
    issueA(0, 4); WAITV("9") COMPUTE(3) BAR()
    // kc4 (even, s=2): A5,B3 -> [B2,A4,A5,B3]
    issueA(1, 5); issueB(1, 3); WAITV("9") BAR() COMPUTE(4)
    // kc5: A6 -> [A5,B3,A6]
    issueA(0, 6); WAITV("9") COMPUTE(5) BAR()
    // kc6 (even, s=3): A7,B4 -> [B3,A6,A7,B4]
    issueA(1, 7); issueB(0, 4); WAITV("9") BAR() COMPUTE(6)
    // kc7: A8 -> [A7,B4,A8]
    issueA(0, 8); WAITV("9") COMPUTE(7) BAR()
    // kc8 (even, s=4): nothing left to issue; drain
    WAITV("0") BAR() COMPUTE(8)

#undef COMPUTE
#undef WAITV
#undef BAR

    // epilogue: C/D layout col=lane&15 (N), row=q*4+reg (M). Stage the full
    // 128x160 bf16 tile through the (now dead) B region, contiguous stores.
    __syncthreads();
    short* eb = (short*)Blds;   // 40960B
    #pragma unroll
    for (int mf = 0; mf < 2; ++mf)
        #pragma unroll
        for (int rr = 0; rr < 4; ++rr) {
            const int m = w * 32 + mf * 16 + (q << 2) + rr;
            #pragma unroll
            for (int nf = 0; nf < 10; ++nf)
                eb[m * 160 + nf * 16 + r] = (short)f2bf(acc[mf][nf][rr]);
        }
    __syncthreads();
    unsigned short* dstc = uhat + ((long)cc * NB + b0) * 160;
    #pragma unroll
    for (int j = 0; j < 10; ++j) {
        const int chunk = j * 256 + tid;
        *(uint4*)(dstc + chunk * 8) = *(const uint4*)(eb + chunk * 8);
    }
}

// ---------------------------------------------------------------------------
// route: one wave per batch row, grid 2048x256. uhat layout [i][b][od]
// (plane stride PL). Softmax from 8-way-spread a partials; agreement u
// fragments preloaded to regs (overlap v-phase); v via tiny LDS; block-
// reduced a partials -> 320 atomics/block onto a_out[blockIdx&7].
// ---------------------------------------------------------------------------
template <int COMPUTE_A, int WRITE_V>
__global__ __launch_bounds__(256) void route_kernel(const unsigned short* __restrict__ uhat,
                                                    const float* __restrict__ a_all,  // [n_prev][8][320]
                                                    int n_prev,
                                                    float* __restrict__ a_out,        // [8][320]
                                                    float* __restrict__ v_out) {
    constexpr long PL = (long)NB * 160;   // i-plane stride (shorts)
    __shared__ float c_sh[320];
    __shared__ float v_lds[4][160];
    __shared__ float a_sh[4][320];
    const int tid = threadIdx.x;
    // --- softmax over input capsules (groups of 32, lane-aligned) ---
    for (int base = 0; base < 320; base += 256) {
        int t = base + tid;
        if (t < 320) {
            float bv = 0.f;
            for (int j = 0; j < n_prev * 8; ++j) bv += a_all[j * 320 + t];
            bv *= (1.0f / 8192.0f);
            float m = bv;
            #pragma unroll
            for (int off = 1; off < 32; off <<= 1) m = fmaxf(m, __shfl_xor(m, off));
            float e = __expf(bv - m);
            float ssum = e;
            #pragma unroll
            for (int off = 1; off < 32; off <<= 1) ssum += __shfl_xor(ssum, off);
            c_sh[t] = e / ssum;
        }
    }
    __syncthreads();

    const int w = tid >> 6;
    const int lane = tid & 63;
    const long row = (long)blockIdx.x * 4 + w;
    const unsigned short* __restrict__ u = uhat + row * 160;

    // preload agreement fragments: lane -> (i = lane&31, oo = (lane>>5)+2*s5)
    ushort4 ua[5][4];
    if (COMPUTE_A) {
        #pragma unroll
        for (int s5 = 0; s5 < 5; ++s5) {
            const int i = lane & 31;
            const int oo = (lane >> 5) + 2 * s5;
            #pragma unroll
            for (int d4 = 0; d4 < 4; ++d4)
                ua[s5][d4] = *(const ushort4*)(u + (long)i * PL + oo * 16 + d4 * 4);
        }
    }

    // v-phase: lanes 0..39, lane q owns od-quad q
    if (lane < 40) {
        const int q = lane;
        const int o = q >> 2;
        float4 sv = {0.f, 0.f, 0.f, 0.f};
        #pragma unroll 8
        for (int i = 0; i < 32; ++i) {
            ushort4 uu = *(const ushort4*)(u + (long)i * PL + q * 4);
            float ci = c_sh[o * 32 + i];
            sv.x += ci * bf2f(uu.x);
            sv.y += ci * bf2f(uu.y);
            sv.z += ci * bf2f(uu.z);
            sv.w += ci * bf2f(uu.w);
        }
        if (WRITE_V) *(float4*)(v_out + row * 160 + q * 4) = sv;
        if (COMPUTE_A) *(float4*)(&v_lds[w][q * 4]) = sv;
    }

    if (COMPUTE_A) {
        asm volatile("s_waitcnt lgkmcnt(0)" ::: "memory");  // v_lds visible wave-locally
        #pragma unroll
        for (int s5 = 0; s5 < 5; ++s5) {
            const int i = lane & 31;
            const int oo = (lane >> 5) + 2 * s5;
            const float* vp = &v_lds[w][oo * 16];
            float accv = 0.f;
            #pragma unroll
            for (int d4 = 0; d4 < 4; ++d4) {
                ushort4 uu = ua[s5][d4];
                float4 vv = *(const float4*)(vp + d4 * 4);
                float p0 = bf2f(uu.x) * vv.x;
                float p1 = bf2f(uu.y) * vv.y;
                float p2 = bf2f(uu.z) * vv.z;
                float p3 = bf2f(uu.w) * vv.w;
                accv += p0 * p0 + p1 * p1 + p2 * p2 + p3 * p3;
            }
            a_sh[w][oo * 32 + i] = sqrtf(accv);
        }
        __syncthreads();
        for (int t = tid; t < 320; t += 256) {
            float s4 = a_sh[0][t] + a_sh[1][t] + a_sh[2][t] + a_sh[3][t];
            atomicAdd(a_out + (blockIdx.x & 7) * 320 + t, s4);
        }
    }
}

// ---------------------------------------------------------------------------
extern "C" void kernel_launch(void* const* d_in, const int* in_sizes, int n_in,
                              void* d_out, int out_size, void* d_ws, size_t ws_size,
                              hipStream_t stream) {
    const float* data = (const float*)d_in[0];
    const float* W = (const float*)d_in[1];
    float* out = (float*)d_out;
    char* ws = (char*)d_ws;

    unsigned short* uhat = (unsigned short*)ws;           // [32][8192][160] bf16, 83,886,080 B
    size_t off = (size_t)NB * IC * OD16 * 2;
    unsigned short* WtImg = (unsigned short*)(ws + off);  // 3,276,800 B
    off += 32L * 5 * 10240 * 2;
    float* a_arr = (float*)(ws + off); off += 3 * 8 * 320 * 4;  // [it][8][320]

    hipLaunchKernelGGL(prep_kernel, dim3(160), dim3(256), 0, stream, W, WtImg, a_arr);
    hipLaunchKernelGGL(gemm_kernel, dim3(64, 32), dim3(256), 0, stream, data, WtImg, uhat);
    hipLaunchKernelGGL((route_kernel<1, 0>), dim3(2048), dim3(256), 0, stream,
                       uhat, a_arr, 0, a_arr + 0 * 2560, out);
    hipLaunchKernelGGL((route_kernel<1, 0>), dim3(2048), dim3(256), 0, stream,
                       uhat, a_arr, 1, a_arr + 1 * 2560, out);
    hipLaunchKernelGGL((route_kernel<0, 1>), dim3(2048), dim3(256), 0, stream,
                       uhat, a_arr, 2, a_arr + 2 * 2560, out);
}

// Round 7
// 164.912 us; speedup vs baseline: 1.4668x; 1.0036x over previous
//
#include <hip/hip_runtime.h>
#include <hip/hip_bf16.h>

#define NB 8192     // batch
#define IC 32       // input capsules
#define ID 288      // input dims (K)
#define OD16 160    // OUT_CAPS*OUT_DIMS (N)

typedef __attribute__((ext_vector_type(8))) short bf16x8;
typedef __attribute__((ext_vector_type(4))) float f32x4;

__device__ __forceinline__ unsigned short f2bf(float f) {
    unsigned int u = __builtin_bit_cast(unsigned int, f);
    u = u + 0x7fffu + ((u >> 16) & 1u);   // round-to-nearest-even
    return (unsigned short)(u >> 16);
}
__device__ __forceinline__ float bf2f(unsigned short h) {
    return __builtin_bit_cast(float, ((unsigned int)h) << 16);
}
// 8 floats -> 8 bf16 via v_cvt_pk_bf16_f32 (compiler-generated)
__device__ __forceinline__ bf16x8 cvt_bf8(const f32x4& a, const f32x4& b) {
    union { __hip_bfloat162 h[4]; bf16x8 v; } u;
    u.h[0] = __float22bfloat162_rn(make_float2(a[0], a[1]));
    u.h[1] = __float22bfloat162_rn(make_float2(a[2], a[3]));
    u.h[2] = __float22bfloat162_rn(make_float2(b[0], b[1]));
    u.h[3] = __float22bfloat162_rn(make_float2(b[2], b[3]));
    return u.v;
}

__device__ __forceinline__ void gld_lds16(const void* g, void* l) {
    __builtin_amdgcn_global_load_lds((const __attribute__((address_space(1))) unsigned int*)g,
                                     (__attribute__((address_space(3))) unsigned int*)l, 16, 0, 0);
}

// ---------------------------------------------------------------------------
// prep: one block per (c, s). LDS-transpose W's [kw x 160] f32 tile to bf16,
// emit B image Bimg[c][kc=9][n=160][4 slots of 16B]: 64B rows, slot s holds
// granule g = s ^ ((n>>1)&3) so a linear global_load_lds dest + slot-swizzled
// ds_read_b128 (2-way banks = free) reconstructs B. 288 = 9*32, no padding.
// Block 0 additionally zeros a_part[3][8][320].
// ---------------------------------------------------------------------------
__global__ __launch_bounds__(256) void prep_kernel(const float* __restrict__ W,
                                                   unsigned short* __restrict__ Bimg,
                                                   float* __restrict__ a_arr) {
    __shared__ short tile[160 * 72];   // row n: 64 k-shorts (+pad), 144B stride
    const int bx = blockIdx.x;
    const int c = bx / 5;
    const int s = bx - c * 5;
    const int t = threadIdx.x;
    if (bx == 0) {
        for (int i = t; i < 3 * 8 * 320; i += 256) a_arr[i] = 0.f;
    }
    const int kw = (s == 4) ? 32 : 64;
    const int nel = kw * 160;
    for (int idx = t; idx < nel; idx += 256) {
        int k = idx / 160;
        int n = idx - k * 160;
        tile[n * 72 + k] = (short)f2bf(W[((long)c * ID + s * 64 + k) * OD16 + n]);
    }
    __syncthreads();
    unsigned short* dst0 = Bimg + ((long)c * 9 + s * 2) * (160 * 32);
    const int nkc = (s == 4) ? 1 : 2;
    for (int kcl = 0; kcl < nkc; ++kcl) {
        unsigned short* dst = dst0 + kcl * (160 * 32);
        for (int p = t; p < 640; p += 256) {
            int n = p >> 2;
            int sl = p & 3;
            int g = sl ^ ((n >> 1) & 3);
            *(uint4*)(dst + p * 8) = *(const uint4*)&tile[n * 72 + kcl * 32 + g * 8];
        }
    }
}

// ---------------------------------------------------------------------------
// gemm: u_hat[c][b][od] = data[b][c][:] @ W[c][:][od], bf16 MFMA 16x16x32.
// A: f32, wave-private LDS dbuf via global_load_lds (full 128B lines),
//    chunk-XOR pre-swizzled source, swizzled ds_read_b128 (2-way = free).
// B: bf16 image, K=32 half-stages (10KB, 64B rows, slot swizzle), dbuf.
// Per kc: issue 7 DMA ops (4A+3B) for kc+1, counted vmcnt(7), 2 barriers.
// LDS 52KB -> 3 blocks/CU (12 waves), 3 independent DMA streams per CU.
// ---------------------------------------------------------------------------
__global__ __launch_bounds__(256) void gemm_kernel(const float* __restrict__ data,
                                                   const unsigned short* __restrict__ Bimg,
                                                   unsigned short* __restrict__ uhat) {
    __shared__ alignas(16) char lds[53248];   // [0,32768): A, [32768,53248): B
    char* const Alds = lds;
    char* const Blds = lds + 32768;
    const int tid = threadIdx.x;
    const int lane = tid & 63;
    const int w = tid >> 6;
    const int q = lane >> 4;     // 0..3
    const int r = lane & 15;
    const int b0 = blockIdx.x * 128;
    const int cc = blockIdx.y;

    // A DMA source: lane ℓ covers (row = w*32 + 8j + (ℓ>>3), chunk (ℓ&7)^((ℓ>>3)&7))
    const float* Ag = data + (long)(b0 + w * 32 + (lane >> 3)) * (IC * ID) + cc * ID
                      + ((lane & 7) ^ ((lane >> 3) & 7)) * 4;
    const unsigned short* Bc = Bimg + (long)cc * (9 * 160 * 32);

    f32x4 acc[2][10];
    #pragma unroll
    for (int i = 0; i < 2; ++i)
        #pragma unroll
        for (int j = 0; j < 10; ++j)
            acc[i][j] = (f32x4){0.f, 0.f, 0.f, 0.f};

    auto issueA = [&](int buf, int kc) {   // 4 DMA ops, wave-private slice
        char* dst = Alds + w * 8192 + buf * 4096;
        const float* src = Ag + kc * 32;
        #pragma unroll
        for (int j = 0; j < 4; ++j)
            gld_lds16(src + (long)j * 8 * (IC * ID), dst + j * 1024);
    };
    auto issueB = [&](int buf, int kc) {   // 3 DMA ops/wave (3rd half-masked)
        const unsigned short* src = Bc + kc * (160 * 32) + (w * 160 + lane) * 8;
        char* dst = Blds + buf * 10240 + w * 2560;
        gld_lds16(src, dst);
        gld_lds16(src + 64 * 8, dst + 1024);
        if (lane < 32) gld_lds16(src + 128 * 8, dst + 2048);
    };

#define COMPUTE(KC)                                                            \
    {                                                                          \
        const char* Ab = Alds + w * 8192 + ((KC) & 1) * 4096;                  \
        const char* Bb = Blds + ((KC) & 1) * 10240;                            \
        const int slot = q ^ ((r >> 1) & 3);                                   \
        bf16x8 bfr[10];                                                        \
        _Pragma("unroll")                                                      \
        for (int nf = 0; nf < 10; ++nf)                                        \
            bfr[nf] = *(const bf16x8*)(Bb + (nf * 16 + r) * 64 + slot * 16);   \
        bf16x8 af[2];                                                          \
        _Pragma("unroll")                                                      \
        for (int mf = 0; mf < 2; ++mf) {                                       \
            const int row = mf * 16 + r;                                       \
            const int c0 = (q * 2) ^ (r & 7);                                  \
            const int c1 = (q * 2 + 1) ^ (r & 7);                              \
            f32x4 alo = *(const f32x4*)(Ab + row * 128 + c0 * 16);             \
            f32x4 ahi = *(const f32x4*)(Ab + row * 128 + c1 * 16);             \
            af[mf] = cvt_bf8(alo, ahi);                                        \
        }                                                                      \
        _Pragma("unroll")                                                      \
        for (int nf = 0; nf < 10; ++nf) {                                      \
            acc[0][nf] = __builtin_amdgcn_mfma_f32_16x16x32_bf16(af[0], bfr[nf], acc[0][nf], 0, 0, 0); \
            acc[1][nf] = __builtin_amdgcn_mfma_f32_16x16x32_bf16(af[1], bfr[nf], acc[1][nf], 0, 0, 0); \
        }                                                                      \
    }

#define WAITV(N)  { asm volatile("s_waitcnt vmcnt(" N ")" ::: "memory");       \
                    __builtin_amdgcn_sched_barrier(0); }
#define BAR()     { __builtin_amdgcn_s_barrier(); }

    // prologue: FIFO A0,B0,A1,B1 (14 ops outstanding)
    issueA(0, 0); issueB(0, 0); issueA(1, 1); issueB(1, 1);
    WAITV("7") BAR() COMPUTE(0) BAR()
    issueA(0, 2); issueB(0, 2); WAITV("7") BAR() COMPUTE(1) BAR()
    issueA(1, 3); issueB(1, 3); WAITV("7") BAR() COMPUTE(2) BAR()
    issueA(0, 4); issueB(0, 4); WAITV("7") BAR() COMPUTE(3) BAR()
    issueA(1, 5); issueB(1, 5); WAITV("7") BAR() COMPUTE(4) BAR()
    issueA(0, 6); issueB(0, 6); WAITV("7") BAR() COMPUTE(5) BAR()
    issueA(1, 7); issueB(1, 7); WAITV("7") BAR() COMPUTE(6) BAR()
    issueA(0, 8); issueB(0, 8); WAITV("7") BAR() COMPUTE(7)
    WAITV("0") BAR() COMPUTE(8)

#undef COMPUTE
#undef WAITV
#undef BAR

    // epilogue: C/D layout col=lane&15 (N), row=q*4+reg (M). Stage 128x160
    // bf16 tile with padded stride 168 shorts (2-way banks on the scatter
    // writes), then contiguous 16B stores to uhat[c][b][od].
    __syncthreads();
    short* eb = (short*)lds;   // [128][168] shorts = 43008B
    #pragma unroll
    for (int mf = 0; mf < 2; ++mf)
        #pragma unroll
        for (int rr = 0; rr < 4; ++rr) {
            const int m = w * 32 + mf * 16 + (q << 2) + rr;
            #pragma unroll
            for (int nf = 0; nf < 10; ++nf)
                eb[m * 168 + nf * 16 + r] = (short)f2bf(acc[mf][nf][rr]);
        }
    __syncthreads();
    unsigned short* dstc = uhat + ((long)cc * NB + b0) * 160;
    #pragma unroll
    for (int j = 0; j < 10; ++j) {
        const int chunk = j * 256 + tid;        // 2560 uint4
        const int row = chunk / 20;
        const int p = chunk - row * 20;
        *(uint4*)(dstc + (long)row * 160 + p * 8) = *(const uint4*)(eb + row * 168 + p * 8);
    }
}

// ---------------------------------------------------------------------------
// route: one wave per batch row, grid 2048x256. uhat layout [i][b][od]
// (plane stride PL). Softmax from 8-way-spread a partials; agreement u
// fragments preloaded to regs (overlap v-phase); v via tiny LDS; block-
// reduced a partials -> 320 atomics/block onto a_out[blockIdx&7].
// ---------------------------------------------------------------------------
template <int COMPUTE_A, int WRITE_V>
__global__ __launch_bounds__(256) void route_kernel(const unsigned short* __restrict__ uhat,
                                                    const float* __restrict__ a_all,  // [n_prev][8][320]
                                                    int n_prev,
                                                    float* __restrict__ a_out,        // [8][320]
                                                    float* __restrict__ v_out) {
    constexpr long PL = (long)NB * 160;   // i-plane stride (shorts)
    __shared__ float c_sh[320];
    __shared__ float v_lds[4][160];
    __shared__ float a_sh[4][320];
    const int tid = threadIdx.x;
    // --- softmax over input capsules (groups of 32, lane-aligned) ---
    for (int base = 0; base < 320; base += 256) {
        int t = base + tid;
        if (t < 320) {
            float bv = 0.f;
            for (int j = 0; j < n_prev * 8; ++j) bv += a_all[j * 320 + t];
            bv *= (1.0f / 8192.0f);
            float m = bv;
            #pragma unroll
            for (int off = 1; off < 32; off <<= 1) m = fmaxf(m, __shfl_xor(m, off));
            float e = __expf(bv - m);
            float ssum = e;
            #pragma unroll
            for (int off = 1; off < 32; off <<= 1) ssum += __shfl_xor(ssum, off);
            c_sh[t] = e / ssum;
        }
    }
    __syncthreads();

    const int w = tid >> 6;
    const int lane = tid & 63;
    const long row = (long)blockIdx.x * 4 + w;
    const unsigned short* __restrict__ u = uhat + row * 160;

    // preload agreement fragments: lane -> (i = lane&31, oo = (lane>>5)+2*s5)
    ushort4 ua[5][4];
    if (COMPUTE_A) {
        #pragma unroll
        for (int s5 = 0; s5 < 5; ++s5) {
            const int i = lane & 31;
            const int oo = (lane >> 5) + 2 * s5;
            #pragma unroll
            for (int d4 = 0; d4 < 4; ++d4)
                ua[s5][d4] = *(const ushort4*)(u + (long)i * PL + oo * 16 + d4 * 4);
        }
    }

    // v-phase: lanes 0..39, lane q owns od-quad q
    if (lane < 40) {
        const int q = lane;
        const int o = q >> 2;
        float4 sv = {0.f, 0.f, 0.f, 0.f};
        #pragma unroll 8
        for (int i = 0; i < 32; ++i) {
            ushort4 uu = *(const ushort4*)(u + (long)i * PL + q * 4);
            float ci = c_sh[o * 32 + i];
            sv.x += ci * bf2f(uu.x);
            sv.y += ci * bf2f(uu.y);
            sv.z += ci * bf2f(uu.z);
            sv.w += ci * bf2f(uu.w);
        }
        if (WRITE_V) *(float4*)(v_out + row * 160 + q * 4) = sv;
        if (COMPUTE_A) *(float4*)(&v_lds[w][q * 4]) = sv;
    }

    if (COMPUTE_A) {
        asm volatile("s_waitcnt lgkmcnt(0)" ::: "memory");  // v_lds visible wave-locally
        #pragma unroll
        for (int s5 = 0; s5 < 5; ++s5) {
            const int i = lane & 31;
            const int oo = (lane >> 5) + 2 * s5;
            const float* vp = &v_lds[w][oo * 16];
            float accv = 0.f;
            #pragma unroll
            for (int d4 = 0; d4 < 4; ++d4) {
                ushort4 uu = ua[s5][d4];
                float4 vv = *(const float4*)(vp + d4 * 4);
                float p0 = bf2f(uu.x) * vv.x;
                float p1 = bf2f(uu.y) * vv.y;
                float p2 = bf2f(uu.z) * vv.z;
                float p3 = bf2f(uu.w) * vv.w;
                accv += p0 * p0 + p1 * p1 + p2 * p2 + p3 * p3;
            }
            a_sh[w][oo * 32 + i] = sqrtf(accv);
        }
        __syncthreads();
        for (int t = tid; t < 320; t += 256) {
            float s4 = a_sh[0][t] + a_sh[1][t] + a_sh[2][t] + a_sh[3][t];
            atomicAdd(a_out + (blockIdx.x & 7) * 320 + t, s4);
        }
    }
}

// ---------------------------------------------------------------------------
extern "C" void kernel_launch(void* const* d_in, const int* in_sizes, int n_in,
                              void* d_out, int out_size, void* d_ws, size_t ws_size,
                              hipStream_t stream) {
    const float* data = (const float*)d_in[0];
    const float* W = (const float*)d_in[1];
    float* out = (float*)d_out;
    char* ws = (char*)d_ws;

    unsigned short* uhat = (unsigned short*)ws;           // [32][8192][160] bf16, 83,886,080 B
    size_t off = (size_t)NB * IC * OD16 * 2;
    unsigned short* Bimg = (unsigned short*)(ws + off);   // [32][9][160][32] bf16, 2,949,120 B
    off += 32L * 9 * 160 * 32 * 2;
    float* a_arr = (float*)(ws + off); off += 3 * 8 * 320 * 4;  // [it][8][320]

    hipLaunchKernelGGL(prep_kernel, dim3(160), dim3(256), 0, stream, W, Bimg, a_arr);
    hipLaunchKernelGGL(gemm_kernel, dim3(64, 32), dim3(256), 0, stream, data, Bimg, uhat);
    hipLaunchKernelGGL((route_kernel<1, 0>), dim3(2048), dim3(256), 0, stream,
                       uhat, a_arr, 0, a_arr + 0 * 2560, out);
    hipLaunchKernelGGL((route_kernel<1, 0>), dim3(2048), dim3(256), 0, stream,
                       uhat, a_arr, 1, a_arr + 1 * 2560, out);
    hipLaunchKernelGGL((route_kernel<0, 1>), dim3(2048), dim3(256), 0, stream,
                       uhat, a_arr, 2, a_arr + 2 * 2560, out);
}